// Round 11
// baseline (1588.596 us; speedup 1.0000x reference)
//
#include <hip/hip_runtime.h>
#include <math.h>

#define TT 8
#define BB 32
#define VV 50257
#define DD 256
#define NN 4096
#define EPS_ 1e-12f

typedef __attribute__((ext_vector_type(8))) short short8;
typedef __attribute__((ext_vector_type(4))) float f32x4;

__device__ __forceinline__ float sigf(float x) { return 1.f / (1.f + expf(-x)); }
__device__ __forceinline__ float softplusf_(float x) { return fmaxf(x, 0.f) + log1pf(expf(-fabsf(x))); }
__device__ __forceinline__ unsigned f2bf(float f) {
  union { float f; unsigned u; } c; c.f = f;
  return (c.u + 0x7FFFu + ((c.u >> 16) & 1u)) >> 16;
}
__device__ __forceinline__ float bf2f(unsigned u16) {
  union { unsigned u; float f; } c; c.u = u16 << 16; return c.f;
}

// ---- block reductions (256-thread blocks only) ----
__device__ __forceinline__ float blk_sum(float v, float* s) {
#pragma unroll
  for (int o = 32; o > 0; o >>= 1) v += __shfl_down(v, o);
  __syncthreads();
  if ((threadIdx.x & 63) == 0) s[threadIdx.x >> 6] = v;
  __syncthreads();
  return s[0] + s[1] + s[2] + s[3];
}
__device__ __forceinline__ float blk_max(float v, float* s) {
#pragma unroll
  for (int o = 32; o > 0; o >>= 1) v = fmaxf(v, __shfl_down(v, o));
  __syncthreads();
  if ((threadIdx.x & 63) == 0) s[threadIdx.x >> 6] = v;
  __syncthreads();
  return fmaxf(fmaxf(s[0], s[1]), fmaxf(s[2], s[3]));
}

// ---- one-time init ----
__global__ void init_k(float* rw, float* ww, float* hpe) {
  int i = blockIdx.x * 256 + threadIdx.x;
  if (i < BB) { rw[(size_t)i * NN] = 1.f; ww[(size_t)i * NN] = 1.f; }
  if (i < BB * DD) hpe[i] = (i & 1) ? 1.f : 0.f;
}

__global__ void cvtw_k(const float* __restrict__ W, unsigned short* __restrict__ Wh, int n4) {
  int i = blockIdx.x * 256 + threadIdx.x;
  if (i >= n4) return;
  float4 v = *(const float4*)(W + (size_t)i * 4);
  uint2 p;
  p.x = f2bf(v.x) | (f2bf(v.y) << 16);
  p.y = f2bf(v.z) | (f2bf(v.w) << 16);
  *(uint2*)(Wh + (size_t)i * 4) = p;
}

__global__ void catlstm_k(const float* __restrict__ Wih, const float* __restrict__ Whh,
                          const float* __restrict__ bih, const float* __restrict__ bhh,
                          unsigned short* __restrict__ Wc, float* __restrict__ cb) {
  int i = blockIdx.x * 256 + threadIdx.x;
  if (i >= 2 * 1024 * 512) return;
  int k = i & 511, np = (i >> 9) & 1023, l = i >> 19;
  int d = np >> 2, gate = np & 3;
  int src = gate * 256 + d;
  float v = (k < 256) ? Wih[((size_t)l * 1024 + src) * 256 + k]
                      : Whh[((size_t)l * 1024 + src) * 256 + (k - 256)];
  Wc[i] = (unsigned short)f2bf(v);
  if (k == 0) cb[l * 1024 + np] = bih[l * 1024 + src] + bhh[l * 1024 + src];
}

__global__ void catrw_k(const float* __restrict__ rW, const float* __restrict__ rb,
                        const float* __restrict__ wW, const float* __restrict__ wb,
                        unsigned short* __restrict__ Wrw, float* __restrict__ brw) {
  int i = blockIdx.x * 256 + threadIdx.x;
  if (i >= 1036 * 256) return;
  int k = i & 255, n = i >> 8;
  float v = (n < 262) ? rW[(size_t)n * 256 + k] : wW[(size_t)(n - 262) * 256 + k];
  Wrw[i] = (unsigned short)f2bf(v);
  if (k == 0) brw[n] = (n < 262) ? rb[n] : wb[n - 262];
}

__global__ void brc_k(const float* __restrict__ fb, const float* __restrict__ rb, float* __restrict__ brc) {
  int i = blockIdx.x * 256 + threadIdx.x;
  if (i < 512) brc[i] = fb[i];
  else if (i < 768) brc[i] = rb[i - 512];
}

// ---- LN1(layer0) of ctx row 0 -> q1b ----
__global__ __launch_bounds__(256) void ln0_k(const float* __restrict__ hpe,
                                             const float* __restrict__ g1, const float* __restrict__ b1,
                                             unsigned short* __restrict__ q1b) {
  __shared__ float s8[8];
  int b = blockIdx.x, d = threadIdx.x;
  float v = hpe[(size_t)b * 256 + d];
  float mu = blk_sum(v, s8) * (1.f / 256.f);
  float dd = v - mu;
  float var = blk_sum(dd * dd, s8) * (1.f / 256.f);
  float rs = rsqrtf(var + 1e-5f);
  q1b[(size_t)b * 256 + d] = (unsigned short)f2bf(dd * rs * g1[d] + b1[d]);
}

// ---- gA f32 device body: 32m x 64n MFMA, K=256 ----
__device__ __forceinline__ void gA32f_dev(const unsigned short* __restrict__ A,
                                          const unsigned short* __restrict__ W,
                                          const float* __restrict__ bias,
                                          float* __restrict__ Cf, int ldc, int Nlim, int nblk) {
  const int tid = threadIdx.x, w = tid >> 6, l = tid & 63, r = l & 15, q = l >> 4;
  const int n = nblk * 64 + w * 16 + r;
  const unsigned short* Wp = W + (size_t)n * 256;
  f32x4 acc0 = {0.f, 0.f, 0.f, 0.f}, acc1 = {0.f, 0.f, 0.f, 0.f};
#pragma unroll
  for (int kt = 0; kt < 8; ++kt) {
    short8 a0 = *(const short8*)(A + r * 256 + kt * 32 + q * 8);
    short8 a1 = *(const short8*)(A + (16 + r) * 256 + kt * 32 + q * 8);
    short8 bf = *(const short8*)(Wp + kt * 32 + q * 8);
    acc0 = __builtin_amdgcn_mfma_f32_16x16x32_bf16(a0, bf, acc0, 0, 0, 0);
    acc1 = __builtin_amdgcn_mfma_f32_16x16x32_bf16(a1, bf, acc1, 0, 0, 0);
  }
  if (n >= Nlim) return;
  float bb = bias[n];
#pragma unroll
  for (int e = 0; e < 4; ++e) {
    int m1 = q * 4 + e, m2 = m1 + 16;
    Cf[(size_t)m1 * ldc + n] = acc0[e] + bb;
    Cf[(size_t)m2 * ldc + n] = acc1[e] + bb;
  }
}

// ---- gA kernel: 2D grid (n-tiles, m-tiles), f32 out ----
__global__ __launch_bounds__(256) void gA_k(const unsigned short* __restrict__ A,
                                            const unsigned short* __restrict__ W,
                                            const float* __restrict__ bias,
                                            float* __restrict__ Cf, int ldc, int Nlim) {
  gA32f_dev(A + (size_t)blockIdx.y * 32 * 256, W, bias,
            Cf + (size_t)blockIdx.y * 32 * ldc, ldc, Nlim, blockIdx.x);
}

// ======= gLN: GEMM with fused row-LN prologue on f32 A =======
// EPI 0: f32 out (qkv layer2); EPI 1: relu->bf16 out (ffn1)
template <int EPI>
__global__ __launch_bounds__(256) void gLN_k(const float* __restrict__ Hf,
                                             const unsigned short* __restrict__ W,
                                             const float* __restrict__ bias,
                                             const float* __restrict__ lng,
                                             const float* __restrict__ lnb,
                                             float* __restrict__ Cf,
                                             unsigned short* __restrict__ Cb, int ldc) {
  const int tid = threadIdx.x, w = tid >> 6, l = tid & 63, r = l & 15, q = l >> 4;
  const int m0 = blockIdx.y * 32;
  const int n = blockIdx.x * 64 + w * 16 + r;
  const float* A0 = Hf + (size_t)(m0 + r) * 256;
  const float* A1 = Hf + (size_t)(m0 + 16 + r) * 256;
  // ---- stats pass ----
  float s1a = 0.f, s2a = 0.f, s1b = 0.f, s2b = 0.f;
#pragma unroll
  for (int kt = 0; kt < 8; ++kt) {
    const float* p0 = A0 + kt * 32 + q * 8;
    const float* p1 = A1 + kt * 32 + q * 8;
#pragma unroll
    for (int j = 0; j < 8; ++j) {
      float v0 = p0[j], v1 = p1[j];
      s1a += v0; s2a += v0 * v0;
      s1b += v1; s2b += v1 * v1;
    }
  }
  s1a += __shfl_xor(s1a, 16); s1a += __shfl_xor(s1a, 32);
  s2a += __shfl_xor(s2a, 16); s2a += __shfl_xor(s2a, 32);
  s1b += __shfl_xor(s1b, 16); s1b += __shfl_xor(s1b, 32);
  s2b += __shfl_xor(s2b, 16); s2b += __shfl_xor(s2b, 32);
  const float mua = s1a * (1.f / 256.f);
  const float rsa = rsqrtf(fmaxf(s2a * (1.f / 256.f) - mua * mua, 0.f) + 1e-5f);
  const float mub = s1b * (1.f / 256.f);
  const float rsb = rsqrtf(fmaxf(s2b * (1.f / 256.f) - mub * mub, 0.f) + 1e-5f);
  // ---- MFMA pass ----
  const unsigned short* Wp = W + (size_t)n * 256;
  f32x4 acc0 = {0.f, 0.f, 0.f, 0.f}, acc1 = {0.f, 0.f, 0.f, 0.f};
#pragma unroll
  for (int kt = 0; kt < 8; ++kt) {
    const int c0 = kt * 32 + q * 8;
    short8 a0, a1;
#pragma unroll
    for (int j = 0; j < 8; ++j) {
      float g = lng[c0 + j], be = lnb[c0 + j];
      a0[j] = (short)f2bf((A0[c0 + j] - mua) * rsa * g + be);
      a1[j] = (short)f2bf((A1[c0 + j] - mub) * rsb * g + be);
    }
    short8 bf = *(const short8*)(Wp + c0);
    acc0 = __builtin_amdgcn_mfma_f32_16x16x32_bf16(a0, bf, acc0, 0, 0, 0);
    acc1 = __builtin_amdgcn_mfma_f32_16x16x32_bf16(a1, bf, acc1, 0, 0, 0);
  }
  float bb = bias[n];
#pragma unroll
  for (int e = 0; e < 4; ++e) {
    int m1 = m0 + q * 4 + e, m2 = m1 + 16;
    float v1 = acc0[e] + bb, v2 = acc1[e] + bb;
    if constexpr (EPI == 0) {
      Cf[(size_t)m1 * ldc + n] = v1;
      Cf[(size_t)m2 * ldc + n] = v2;
    } else {
      Cb[(size_t)m1 * ldc + n] = (unsigned short)f2bf(fmaxf(v1, 0.f));
      Cb[(size_t)m2 * ldc + n] = (unsigned short)f2bf(fmaxf(v2, 0.f));
    }
  }
}

// ---- gC kernel: 32m x 64n, templated K, out f32 = acc + bias + resid ----
template <int K>
__global__ __launch_bounds__(256) void gC_k(const unsigned short* __restrict__ A,
                                            const unsigned short* __restrict__ W,
                                            const float* __restrict__ bias,
                                            const float* __restrict__ resid,
                                            float* __restrict__ Hout) {
  const int tid = threadIdx.x, w = tid >> 6, l = tid & 63, r = l & 15, q = l >> 4;
  const int n = blockIdx.x * 64 + w * 16 + r;
  const int m0 = blockIdx.y * 32;
  const unsigned short* Ap = A + (size_t)m0 * K;
  const unsigned short* Wp = W + (size_t)n * K;
  f32x4 acc0 = {0.f, 0.f, 0.f, 0.f}, acc1 = {0.f, 0.f, 0.f, 0.f};
#pragma unroll 4
  for (int kt = 0; kt < K / 32; ++kt) {
    short8 a0 = *(const short8*)(Ap + (size_t)r * K + kt * 32 + q * 8);
    short8 a1 = *(const short8*)(Ap + (size_t)(16 + r) * K + kt * 32 + q * 8);
    short8 bf = *(const short8*)(Wp + kt * 32 + q * 8);
    acc0 = __builtin_amdgcn_mfma_f32_16x16x32_bf16(a0, bf, acc0, 0, 0, 0);
    acc1 = __builtin_amdgcn_mfma_f32_16x16x32_bf16(a1, bf, acc1, 0, 0, 0);
  }
  float bb = bias[n];
#pragma unroll
  for (int e = 0; e < 4; ++e) {
    int m1 = m0 + q * 4 + e, m2 = m1 + 16;
    Hout[(size_t)m1 * 256 + n] = acc0[e] + bb + resid[(size_t)m1 * 256 + n];
    Hout[(size_t)m2 * 256 + n] = acc1[e] + bb + resid[(size_t)m2 * 256 + n];
  }
}

// ---- addLN: row-LN over 32 rows/block of f32 H -> bf16 Xb (+optional f32 c_out) ----
__global__ __launch_bounds__(256) void addLN_k(const float* __restrict__ H,
                                               const float* __restrict__ g,
                                               const float* __restrict__ be,
                                               unsigned short* __restrict__ Xb, int xstride,
                                               float* __restrict__ c_out) {
  const int tid = threadIdx.x, w = tid >> 6, l = tid & 63;
  const int m0 = blockIdx.x * 32;
  const float4 g4 = *(const float4*)(g + l * 4);
  const float4 b4 = *(const float4*)(be + l * 4);
#pragma unroll
  for (int i = 0; i < 8; ++i) {
    int row = m0 + w * 8 + i;
    float4 v = *(const float4*)(H + (size_t)row * 256 + l * 4);
    float s1 = v.x + v.y + v.z + v.w;
    float s2 = v.x * v.x + v.y * v.y + v.z * v.z + v.w * v.w;
#pragma unroll
    for (int o = 32; o > 0; o >>= 1) { s1 += __shfl_xor(s1, o); s2 += __shfl_xor(s2, o); }
    float mu = s1 * (1.f / 256.f);
    float var = fmaxf(s2 * (1.f / 256.f) - mu * mu, 0.f);
    float rs = rsqrtf(var + 1e-5f);
    float y0 = (v.x - mu) * rs * g4.x + b4.x;
    float y1 = (v.y - mu) * rs * g4.y + b4.y;
    float y2 = (v.z - mu) * rs * g4.z + b4.z;
    float y3 = (v.w - mu) * rs * g4.w + b4.w;
    uint2 pk;
    pk.x = f2bf(y0) | (f2bf(y1) << 16);
    pk.y = f2bf(y2) | (f2bf(y3) << 16);
    *(uint2*)(Xb + (size_t)row * xstride + l * 4) = pk;
    if (c_out) {
      float4 cv = make_float4(y0, y1, y2, y3);
      *(float4*)(c_out + (size_t)row * 256 + l * 4) = cv;
    }
  }
}

// ---- aux: rw-param GEMM (blocks 0..16) + film GEMM (17..28) ----
__global__ __launch_bounds__(256) void auxg_k(const unsigned short* __restrict__ cfinb,
                                              const unsigned short* __restrict__ Wrw,
                                              const float* __restrict__ brw, float* __restrict__ rpwp,
                                              const unsigned short* __restrict__ record_b,
                                              const unsigned short* __restrict__ FRw,
                                              const float* __restrict__ brc, float* __restrict__ fp) {
  if (blockIdx.x < 17) gA32f_dev(cfinb, Wrw, brw, rpwp, 1036, 1036, blockIdx.x);
  else gA32f_dev(record_b, FRw, brc, fp, 768, 768, blockIdx.x - 17);
}

// ---- full multi-head attention over S<=9 rows (layer 1), bf16 out ----
__global__ __launch_bounds__(128) void attn_k(const float* __restrict__ qkv,
                                              unsigned short* __restrict__ ao, int S) {
  int bh = blockIdx.x;
  int b = bh >> 2, h = bh & 3;
  __shared__ float q[9][64], k[9][64], v[9][64], lg[9][12];
  int tid = threadIdx.x;
  for (int i = tid; i < S * 64; i += 128) {
    int s = i >> 6, d = i & 63;
    const float* base = qkv + (size_t)(s * BB + b) * 768 + h * 64 + d;
    q[s][d] = base[0]; k[s][d] = base[256]; v[s][d] = base[512];
  }
  __syncthreads();
  for (int p = tid; p < S * S; p += 128) {
    int s = p / S, t2 = p % S;
    float acc = 0.f;
    for (int d = 0; d < 64; ++d) acc += q[s][d] * k[t2][d];
    lg[s][t2] = acc * 0.125f;
  }
  __syncthreads();
  if (tid < S) {
    float mx = -1e30f;
    for (int t2 = 0; t2 < S; ++t2) mx = fmaxf(mx, lg[tid][t2]);
    float sum = 0.f;
    for (int t2 = 0; t2 < S; ++t2) { float e = expf(lg[tid][t2] - mx); lg[tid][t2] = e; sum += e; }
    float inv = 1.f / sum;
    for (int t2 = 0; t2 < S; ++t2) lg[tid][t2] *= inv;
  }
  __syncthreads();
  for (int i = tid; i < S * 64; i += 128) {
    int s = i >> 6, d = i & 63;
    float o = 0.f;
    for (int t2 = 0; t2 < S; ++t2) o += lg[s][t2] * v[t2][d];
    ao[(size_t)(s * BB + b) * 256 + h * 64 + d] = (unsigned short)f2bf(o);
  }
}

// ---- last-row-only attention (layer 2), bf16 out ----
__global__ __launch_bounds__(64) void attnl_k(const float* __restrict__ qkv,
                                              unsigned short* __restrict__ ao, int S) {
  int bh = blockIdx.x;
  int b = bh >> 2, h = bh & 3;
  int d = threadIdx.x;
  __shared__ float sc[9];
  float qd = qkv[(size_t)((S - 1) * BB + b) * 768 + h * 64 + d];
  for (int j = 0; j < S; ++j) {
    float p = qd * qkv[(size_t)(j * BB + b) * 768 + h * 64 + 256 + d];
#pragma unroll
    for (int o = 32; o > 0; o >>= 1) p += __shfl_down(p, o);
    if (d == 0) sc[j] = p * 0.125f;
  }
  __syncthreads();
  float mx = -1e30f;
  for (int j = 0; j < S; ++j) mx = fmaxf(mx, sc[j]);
  float pj[9], sum = 0.f;
  for (int j = 0; j < S; ++j) { pj[j] = expf(sc[j] - mx); sum += pj[j]; }
  float inv = 1.f / sum;
  float o = 0.f;
  for (int j = 0; j < S; ++j) o += pj[j] * inv * qkv[(size_t)(j * BB + b) * 768 + h * 64 + 512 + d];
  ao[(size_t)b * 256 + h * 64 + d] = (unsigned short)f2bf(o);
}

// ======= LSTM MFMA GEMM (K=512, gate-interleaved N=1024) + pointwise epilogue =======
template <int LAST>
__global__ __launch_bounds__(256) void gL_k(const unsigned short* __restrict__ A,
                                            const unsigned short* __restrict__ W,
                                            const float* __restrict__ cbias,
                                            float* __restrict__ cx,
                                            unsigned short* __restrict__ li_own,
                                            unsigned short* __restrict__ li_next,
                                            const float* __restrict__ c_outp,
                                            unsigned short* __restrict__ cfinb,
                                            unsigned short* __restrict__ record_b) {
  __shared__ float g[32][68];
  const int tid = threadIdx.x, w = tid >> 6, l = tid & 63, r = l & 15, q = l >> 4;
  const int n = blockIdx.x * 64 + w * 16 + r;
  const unsigned short* Wp = W + (size_t)n * 512;
  f32x4 acc0 = {0.f, 0.f, 0.f, 0.f}, acc1 = {0.f, 0.f, 0.f, 0.f};
#pragma unroll 4
  for (int kt = 0; kt < 16; ++kt) {
    short8 a0 = *(const short8*)(A + (size_t)r * 512 + kt * 32 + q * 8);
    short8 a1 = *(const short8*)(A + (size_t)(16 + r) * 512 + kt * 32 + q * 8);
    short8 bf = *(const short8*)(Wp + kt * 32 + q * 8);
    acc0 = __builtin_amdgcn_mfma_f32_16x16x32_bf16(a0, bf, acc0, 0, 0, 0);
    acc1 = __builtin_amdgcn_mfma_f32_16x16x32_bf16(a1, bf, acc1, 0, 0, 0);
  }
  float bb = cbias[n];
  int nb = w * 16 + r;
#pragma unroll
  for (int e = 0; e < 4; ++e) {
    g[q * 4 + e][nb] = acc0[e] + bb;
    g[16 + q * 4 + e][nb] = acc1[e] + bb;
  }
  __syncthreads();
#pragma unroll
  for (int h2 = 0; h2 < 2; ++h2) {
    int u = tid + 256 * h2;
    int b = u >> 4, dd = u & 15;
    int dg = blockIdx.x * 16 + dd;
    float gi = g[b][dd * 4 + 0], gf = g[b][dd * 4 + 1];
    float gg = g[b][dd * 4 + 2], go = g[b][dd * 4 + 3];
    float c = sigf(gf) * cx[b * 256 + dg] + sigf(gi) * tanhf(gg);
    float hN = sigf(go) * tanhf(c);
    cx[b * 256 + dg] = c;
    li_own[(size_t)b * 512 + 256 + dg] = (unsigned short)f2bf(hN);
    if constexpr (LAST) {
      record_b[b * 256 + dg] = (unsigned short)f2bf(hN);
      cfinb[b * 256 + dg] = (unsigned short)f2bf(c_outp[b * 256 + dg] + hN);
    } else {
      li_next[(size_t)b * 512 + dg] = (unsigned short)f2bf(hN);
    }
  }
}

// ---- xin pointwise: FiLM nonlin + emb + gated read + PE -> hpe row; LN1 -> q1b ----
__global__ __launch_bounds__(256) void xinpw_k(const int* __restrict__ tokens,
                                               const float* __restrict__ embW,
                                               const float* __restrict__ fp,
                                               const float* __restrict__ rvec,
                                               const float* __restrict__ g1, const float* __restrict__ b1,
                                               float* __restrict__ hpe,
                                               unsigned short* __restrict__ q1b, int t) {
  __shared__ float s8[8];
  int b = blockIdx.x, d = threadIdx.x;
  float gam = 1.f + tanhf(fp[(size_t)b * 768 + d]);
  float bet = fp[(size_t)b * 768 + 256 + d];
  float rg = sigf(fp[(size_t)b * 768 + 512 + d]);
  int tok = tokens[t * BB + b];
  float emb = embW[(size_t)tok * 256 + d];
  float ang = (float)(t + 1) * expf(-logf(10000.f) * (float)(d & ~1) / 256.f);
  float pe = (d & 1) ? cosf(ang) : sinf(ang);
  float x = gam * emb + bet + rg * rvec[b * 256 + d] + pe;
  hpe[((size_t)(t + 1) * BB + b) * 256 + d] = x;
  float mu = blk_sum(x, s8) * (1.f / 256.f);
  float dd = x - mu;
  float var = blk_sum(dd * dd, s8) * (1.f / 256.f);
  float rs = rsqrtf(var + 1e-5f);
  q1b[((size_t)(t + 1) * BB + b) * 256 + d] = (unsigned short)f2bf(dd * rs * g1[d] + b1[d]);
}

// ======= fused head (blocks 0..785) + MFMA passA (786..786+1024) =======
__global__ __launch_bounds__(256) void fusePA_k(const unsigned short* __restrict__ Wh,
                                                const unsigned short* __restrict__ Ah,
                                                const float* __restrict__ hb,
                                                float* __restrict__ out,
                                                const unsigned short* __restrict__ mem,
                                                const float* __restrict__ rpwp,
                                                float* __restrict__ dr,
                                                float* __restrict__ dw,
                                                float* __restrict__ nrm) {
  __shared__ unsigned short kS[4][256];
  const int bid = blockIdx.x;
  const int tid = threadIdx.x;
  if (bid < 786) {
    const int w = tid >> 6, l = tid & 63;
    const int r = l & 15, q = l >> 4;
    const int n = bid * 64 + w * 16 + r;
    const int nc = n < VV ? n : VV - 1;
    const short* Ap = (const short*)Ah;
    const short* Wp = (const short*)Wh + (size_t)nc * 256;
    short8 a0[8], a1[8], bf[8];
#pragma unroll
    for (int kt = 0; kt < 8; ++kt) {
      a0[kt] = *(const short8*)(Ap + r * 256 + kt * 32 + q * 8);
      a1[kt] = *(const short8*)(Ap + (16 + r) * 256 + kt * 32 + q * 8);
      bf[kt] = *(const short8*)(Wp + kt * 32 + q * 8);
    }
    f32x4 acc0 = {0.f, 0.f, 0.f, 0.f}, acc1 = {0.f, 0.f, 0.f, 0.f};
#pragma unroll
    for (int kt = 0; kt < 8; ++kt) {
      acc0 = __builtin_amdgcn_mfma_f32_16x16x32_bf16(a0[kt], bf[kt], acc0, 0, 0, 0);
      acc1 = __builtin_amdgcn_mfma_f32_16x16x32_bf16(a1[kt], bf[kt], acc1, 0, 0, 0);
    }
    if (n < VV) {
      float bb = hb[n];
#pragma unroll
      for (int e = 0; e < 4; ++e) {
        int m = q * 4 + e;
        out[(size_t)m * VV + n] = acc0[e] + bb;
        out[(size_t)(16 + m) * VV + n] = acc1[e] + bb;
      }
    }
    return;
  }
  const int idx = bid - 786;
  const int bx = idx & 31, by = idx >> 5;
  {
    float kr = rpwp[(size_t)by * 1036 + tid];
    float kw = rpwp[(size_t)by * 1036 + 262 + tid];
    unsigned krh = f2bf(kr), kwh = f2bf(kw);
    kS[0][tid] = (unsigned short)krh;
    kS[1][tid] = (unsigned short)kwh;
    kS[2][tid] = (unsigned short)f2bf(kr - bf2f(krh));
    kS[3][tid] = (unsigned short)f2bf(kw - bf2f(kwh));
  }
  __syncthreads();
  const int w = tid >> 6, l = tid & 63, col = l & 15, ko = (l >> 4) * 8;
  short8 bfrag[8];
#pragma unroll
  for (int kt = 0; kt < 8; ++kt) {
    if (col < 4) bfrag[kt] = *(const short8*)(&kS[col][kt * 32 + ko]);
    else bfrag[kt] = short8{0, 0, 0, 0, 0, 0, 0, 0};
  }
  const int base = bx * 128 + w * 32;
  const unsigned short* Ap0 = mem + ((size_t)by * NN + base + col) * 256 + ko;
  const unsigned short* Ap1 = mem + ((size_t)by * NN + base + 16 + col) * 256 + ko;
  f32x4 acc0 = {0.f, 0.f, 0.f, 0.f}, acc1 = {0.f, 0.f, 0.f, 0.f};
  float pn0 = 0.f, pn1 = 0.f;
#pragma unroll
  for (int kt = 0; kt < 8; ++kt) {
    short8 a0 = *(const short8*)(Ap0 + kt * 32);
    short8 a1 = *(const short8*)(Ap1 + kt * 32);
    acc0 = __builtin_amdgcn_mfma_f32_16x16x32_bf16(a0, bfrag[kt], acc0, 0, 0, 0);
    acc1 = __builtin_amdgcn_mfma_f32_16x16x32_bf16(a1, bfrag[kt], acc1, 0, 0, 0);
#pragma unroll
    for (int j = 0; j < 8; ++j) {
      float v0 = bf2f((unsigned short)a0[j]);
      float v1 = bf2f((unsigned short)a1[j]);
      pn0 += v0 * v0;
      pn1 += v1 * v1;
    }
  }
  pn0 += __shfl_xor(pn0, 16); pn0 += __shfl_xor(pn0, 32);
  pn1 += __shfl_xor(pn1, 16); pn1 += __shfl_xor(pn1, 32);
  if (l < 16) {
    nrm[(size_t)by * NN + base + l] = pn0;
    nrm[(size_t)by * NN + base + 16 + l] = pn1;
  }
#pragma unroll
  for (int e = 0; e < 4; ++e) {
    float s0 = acc0[e] + __shfl_xor(acc0[e], 2);
    float s1 = acc1[e] + __shfl_xor(acc1[e], 2);
    int row = (l >> 4) * 4 + e;
    if (col == 0) {
      dr[(size_t)by * NN + base + row] = s0;
      dr[(size_t)by * NN + base + 16 + row] = s1;
    } else if (col == 1) {
      dw[(size_t)by * NN + base + row] = s0;
      dw[(size_t)by * NN + base + 16 + row] = s1;
    }
  }
}

// ---- addressing ----
__global__ __launch_bounds__(256) void addr_k(const float* __restrict__ dr,
                                              const float* __restrict__ dw,
                                              const float* __restrict__ nrm,
                                              const float* __restrict__ rpwp,
                                              float* rw, float* ww,
                                              float* __restrict__ ea,
                                              float* __restrict__ rvec) {
  __shared__ float wg[4096];
  __shared__ float s8[8];
  int head = blockIdx.x & 1, b = blockIdx.x >> 1;
  int tid = threadIdx.x;
  const float* p = rpwp + (size_t)b * 1036 + (head ? 262 : 0);
  const float* dot = (head ? dw : dr) + (size_t)b * NN;
  const float* n2 = nrm + (size_t)b * NN;
  float* wout = (head ? ww : rw) + (size_t)b * NN;

  float kv = p[tid];
  float kn = sqrtf(blk_sum(kv * kv, s8)) + EPS_;
  float beta = p[256], gate = p[257], sh0 = p[258], sh1 = p[259], sh2 = p[260], gamma = p[261];
  float spb = softplusf_(beta);
  float g = sigf(gate);
  float mx3 = fmaxf(sh0, fmaxf(sh1, sh2));
  float e0 = expf(sh0 - mx3), e1 = expf(sh1 - mx3), e2 = expf(sh2 - mx3);
  float esum = e0 + e1 + e2;
  float s0 = e0 / esum, s1 = e1 / esum, s2 = e2 / esum;
  float gp = 1.f + softplusf_(gamma);

  float l[16];
  float lmax = -1e30f;
#pragma unroll
  for (int i = 0; i < 16; ++i) {
    int n = tid + i * 256;
    float cs = dot[n] / ((sqrtf(n2[n]) + EPS_) * kn);
    l[i] = spb * cs;
    lmax = fmaxf(lmax, l[i]);
  }
  float Mx = blk_max(lmax, s8);
  float es = 0.f;
#pragma unroll
  for (int i = 0; i < 16; ++i) { l[i] = expf(l[i] - Mx); es += l[i]; }
  float SS = blk_sum(es, s8);
  float inv = 1.f / SS;
#pragma unroll
  for (int i = 0; i < 16; ++i) {
    int n = tid + i * 256;
    wg[n] = g * l[i] * inv + (1.f - g) * wout[n];
  }
  __syncthreads();
  float wt[16];
  float wsum = 0.f;
#pragma unroll
  for (int i = 0; i < 16; ++i) {
    int n = tid + i * 256;
    float sh = s0 * wg[(n + 1) & 4095] + s1 * wg[n] + s2 * wg[(n + 4095) & 4095];
    wt[i] = powf(sh + EPS_, gp);
    wsum += wt[i];
  }
  float WS = blk_sum(wsum, s8) + EPS_;
  float winv = 1.f / WS;
#pragma unroll
  for (int i = 0; i < 16; ++i) wout[tid + i * 256] = wt[i] * winv;

  if (head) {
    ea[(size_t)b * 512 + tid] = sigf(p[262 + tid]);
    ea[(size_t)b * 512 + 256 + tid] = tanhf(p[518 + tid]);
  } else {
    rvec[(size_t)b * 256 + tid] = 0.f;
  }
}

// ---- pass B over bf16 memory: erase/add + fused r = rw . mem_new ----
template <int FIRST>
__global__ __launch_bounds__(256) void passB_k(unsigned short* mem, const float* __restrict__ ww,
                                               const float* __restrict__ rw,
                                               const float* __restrict__ ea,
                                               float* __restrict__ rvec) {
  __shared__ float eS[256], aS[256];
  __shared__ float rred[4][256];
  int b = blockIdx.y, tid = threadIdx.x;
  eS[tid] = ea[(size_t)b * 512 + tid];
  aS[tid] = ea[(size_t)b * 512 + 256 + tid];
  __syncthreads();
  int w = tid >> 6, lane = tid & 63;
  float4 e4 = *(float4*)&eS[lane * 4];
  float4 a4 = *(float4*)&aS[lane * 4];
  float4 racc = make_float4(0.f, 0.f, 0.f, 0.f);
  int n0 = blockIdx.x * 128 + w * 32;
  for (int rr = 0; rr < 32; ++rr) {
    int n = n0 + rr;
    float wt = ww[(size_t)b * NN + n];
    float rwv = rw[(size_t)b * NN + n];
    unsigned short* row = mem + ((size_t)b * NN + n) * 256;
    float m0, m1, m2, m3;
    if (FIRST) {
      m0 = wt * a4.x; m1 = wt * a4.y; m2 = wt * a4.z; m3 = wt * a4.w;
    } else {
      uint2 p = *(const uint2*)(row + lane * 4);
      m0 = bf2f(p.x & 0xffffu) * (1.f - wt * e4.x) + wt * a4.x;
      m1 = bf2f(p.x >> 16) * (1.f - wt * e4.y) + wt * a4.y;
      m2 = bf2f(p.y & 0xffffu) * (1.f - wt * e4.z) + wt * a4.z;
      m3 = bf2f(p.y >> 16) * (1.f - wt * e4.w) + wt * a4.w;
    }
    uint2 pk;
    pk.x = f2bf(m0) | (f2bf(m1) << 16);
    pk.y = f2bf(m2) | (f2bf(m3) << 16);
    *(uint2*)(row + lane * 4) = pk;
    racc.x += rwv * m0; racc.y += rwv * m1; racc.z += rwv * m2; racc.w += rwv * m3;
  }
  rred[w][lane * 4 + 0] = racc.x;
  rred[w][lane * 4 + 1] = racc.y;
  rred[w][lane * 4 + 2] = racc.z;
  rred[w][lane * 4 + 3] = racc.w;
  __syncthreads();
  float s = rred[0][tid] + rred[1][tid] + rred[2][tid] + rred[3][tid];
  atomicAdd(rvec + (size_t)b * 256 + tid, s);
}

extern "C" void kernel_launch(void* const* d_in, const int* in_sizes, int n_in,
                              void* d_out, int out_size, void* d_ws, size_t ws_size,
                              hipStream_t stream) {
  const int* tokens = (const int*)d_in[0];
  const float* emb_W = (const float*)d_in[1];
  const float* read_gate_W = (const float*)d_in[2];
  const float* read_gate_b = (const float*)d_in[3];
  const float* film_W = (const float*)d_in[4];
  const float* film_b = (const float*)d_in[5];
  const float* t_Wqkv = (const float*)d_in[6];
  const float* t_bqkv = (const float*)d_in[7];
  const float* t_Wo = (const float*)d_in[8];
  const float* t_bo = (const float*)d_in[9];
  const float* t_ln1_g = (const float*)d_in[10];
  const float* t_ln1_b = (const float*)d_in[11];
  const float* t_ln2_g = (const float*)d_in[12];
  const float* t_ln2_b = (const float*)d_in[13];
  const float* t_W1 = (const float*)d_in[14];
  const float* t_b1 = (const float*)d_in[15];
  const float* t_W2 = (const float*)d_in[16];
  const float* t_b2 = (const float*)d_in[17];
  const float* out_ln_g = (const float*)d_in[18];
  const float* out_ln_b = (const float*)d_in[19];
  const float* lstm_Wih = (const float*)d_in[20];
  const float* lstm_Whh = (const float*)d_in[21];
  const float* lstm_bih = (const float*)d_in[22];
  const float* lstm_bhh = (const float*)d_in[23];
  const float* head_W = (const float*)d_in[24];
  const float* head_b = (const float*)d_in[25];
  const float* read_W = (const float*)d_in[26];
  const float* read_b = (const float*)d_in[27];
  const float* write_W = (const float*)d_in[28];
  const float* write_b = (const float*)d_in[29];
  float* out = (float*)d_out;

  float* ws = (float*)d_ws;
  size_t off = 0;
  // ---- zero-initialized region ----
  float* read_w = ws + off; off += (size_t)BB * NN;
  float* write_w = ws + off; off += (size_t)BB * NN;
  float* cx = ws + off; off += 2 * BB * DD;
  float* r_vec = ws + off; off += BB * DD;
  float* dot_r = ws + off; off += (size_t)BB * NN;
  float* dot_w = ws + off; off += (size_t)BB * NN;
  float* norm2 = ws + off; off += (size_t)BB * NN;
  unsigned short* record_b = (unsigned short*)(ws + off); off += BB * DD / 2;
  unsigned short* lstm_in_b = (unsigned short*)(ws + off); off += 2 * BB * 512 / 2;
  size_t zero_floats = off;
  // ---- not zeroed ----
  unsigned short* memory = (unsigned short*)(ws + off); off += (size_t)BB * NN * DD / 2;
  float* hpe = ws + off; off += 9 * BB * DD;
  float* h = ws + off; off += 9 * BB * DD;
  float* h2 = ws + off; off += BB * DD;
  float* qkvC = ws + off; off += 9 * BB * 768;
  float* qkv2 = ws + off; off += 9 * BB * 768;
  float* fp = ws + off; off += BB * 768;
  float* c_out = ws + off; off += BB * DD;
  float* rpwp = ws + off; off += BB * 1036;
  float* ea = ws + off; off += BB * 2 * DD;
  unsigned short* q1b = (unsigned short*)(ws + off); off += 9 * BB * DD / 2;
  unsigned short* ao1_b = (unsigned short*)(ws + off); off += 9 * BB * DD / 2;
  unsigned short* ao2_b = (unsigned short*)(ws + off); off += BB * DD / 2;
  unsigned short* mid_b = (unsigned short*)(ws + off); off += 9 * BB * 1024 / 2;
  unsigned short* cfinb = (unsigned short*)(ws + off); off += BB * DD / 2;
  unsigned short* Wh = (unsigned short*)(ws + off); off += (size_t)VV * 256 / 2;
  unsigned short* Wq_b = (unsigned short*)(ws + off); off += 2 * 768 * 256 / 2;
  unsigned short* Wo_b = (unsigned short*)(ws + off); off += 2 * 256 * 256 / 2;
  unsigned short* W1_b = (unsigned short*)(ws + off); off += 2 * 1024 * 256 / 2;
  unsigned short* W2_b = (unsigned short*)(ws + off); off += 2 * 256 * 1024 / 2;
  unsigned short* Wc_b = (unsigned short*)(ws + off); off += 2 * 1024 * 512 / 2;
  unsigned short* Wrw_b = (unsigned short*)(ws + off); off += 1088 * 256 / 2;
  unsigned short* FR_b = (unsigned short*)(ws + off); off += 768 * 256 / 2;
  float* cb2 = ws + off; off += 2 * 1024;
  float* brw = ws + off; off += 1040;
  float* brc = ws + off; off += 768;
  if (ws_size < off * sizeof(float)) return;

  (void)hipMemsetAsync(ws, 0, zero_floats * sizeof(float), stream);
  (void)hipMemsetAsync(Wrw_b + (size_t)1036 * 256, 0, (size_t)52 * 256 * 2, stream);
  init_k<<<32, 256, 0, stream>>>(read_w, write_w, hpe);
  cvtw_k<<<(VV * 256 / 4 + 255) / 256, 256, 0, stream>>>(head_W, Wh, VV * 256 / 4);
  cvtw_k<<<(2 * 768 * 256 / 4 + 255) / 256, 256, 0, stream>>>(t_Wqkv, Wq_b, 2 * 768 * 256 / 4);
  cvtw_k<<<(2 * 256 * 256 / 4 + 255) / 256, 256, 0, stream>>>(t_Wo, Wo_b, 2 * 256 * 256 / 4);
  cvtw_k<<<(2 * 1024 * 256 / 4 + 255) / 256, 256, 0, stream>>>(t_W1, W1_b, 2 * 1024 * 256 / 4);
  cvtw_k<<<(2 * 256 * 1024 / 4 + 255) / 256, 256, 0, stream>>>(t_W2, W2_b, 2 * 256 * 1024 / 4);
  cvtw_k<<<(512 * 256 / 4 + 255) / 256, 256, 0, stream>>>(film_W, FR_b, 512 * 256 / 4);
  cvtw_k<<<(256 * 256 / 4 + 255) / 256, 256, 0, stream>>>(read_gate_W, FR_b + 512 * 256, 256 * 256 / 4);
  catlstm_k<<<4096, 256, 0, stream>>>(lstm_Wih, lstm_Whh, lstm_bih, lstm_bhh, Wc_b, cb2);
  catrw_k<<<1036, 256, 0, stream>>>(read_W, read_b, write_W, write_b, Wrw_b, brw);
  brc_k<<<3, 256, 0, stream>>>(film_b, read_gate_b, brc);
  ln0_k<<<BB, 256, 0, stream>>>(hpe, t_ln1_g, t_ln1_b, q1b);
  gA_k<<<dim3(12, 1), 256, 0, stream>>>(q1b, Wq_b, t_bqkv, qkvC, 768, 768);
  gA_k<<<dim3(12, 1), 256, 0, stream>>>(record_b, FR_b, brc, fp, 768, 768);  // film t=0

  for (int t = 0; t < TT; ++t) {
    const int S = t + 2;

    xinpw_k<<<BB, 256, 0, stream>>>(tokens, emb_W, fp, r_vec, t_ln1_g, t_ln1_b, hpe, q1b, t);
    gA_k<<<dim3(12, 1), 256, 0, stream>>>(q1b + (size_t)(t + 1) * BB * 256, Wq_b, t_bqkv,
                                          qkvC + (size_t)(t + 1) * BB * 768, 768, 768);
    attn_k<<<BB * 4, 128, 0, stream>>>(qkvC, ao1_b, S);
    gC_k<256><<<dim3(4, S), 256, 0, stream>>>(ao1_b, Wo_b, t_bo, hpe, h);
    gLN_k<1><<<dim3(16, S), 256, 0, stream>>>(h, W1_b, t_b1, t_ln2_g, t_ln2_b,
                                              nullptr, mid_b, 1024);
    gC_k<1024><<<dim3(4, S), 256, 0, stream>>>(mid_b, W2_b, t_b2, h, h);
    gLN_k<0><<<dim3(12, S), 256, 0, stream>>>(h, Wq_b + 768 * 256, t_bqkv + 768,
                                              t_ln1_g + 256, t_ln1_b + 256, qkv2, nullptr, 768);
    attnl_k<<<BB * 4, 64, 0, stream>>>(qkv2, ao2_b, S);
    gC_k<256><<<dim3(4, 1), 256, 0, stream>>>(ao2_b, Wo_b + 256 * 256, t_bo + 256,
                                              h + (size_t)(S - 1) * BB * 256, h2);
    gLN_k<1><<<dim3(16, 1), 256, 0, stream>>>(h2, W1_b + 1024 * 256, t_b1 + 1024,
                                              t_ln2_g + 256, t_ln2_b + 256, nullptr, mid_b, 1024);
    gC_k<1024><<<dim3(4, 1), 256, 0, stream>>>(mid_b, W2_b + 256 * 1024, t_b2 + 256, h2, h2);
    addLN_k<<<1, 256, 0, stream>>>(h2, out_ln_g, out_ln_b, lstm_in_b, 512, c_out);
    // LSTM
    gL_k<0><<<16, 256, 0, stream>>>(lstm_in_b, Wc_b, cb2, cx, lstm_in_b, lstm_in_b + BB * 512,
                                    nullptr, nullptr, nullptr);
    gL_k<1><<<16, 256, 0, stream>>>(lstm_in_b + BB * 512, Wc_b + (size_t)1024 * 512, cb2 + 1024,
                                    cx + BB * DD, lstm_in_b + BB * 512, nullptr, c_out, cfinb, record_b);
    // aux GEMMs then head || passA
    if (t < TT - 1) {
      auxg_k<<<29, 256, 0, stream>>>(cfinb, Wrw_b, brw, rpwp, record_b, FR_b, brc, fp);
      if (t > 0)
        fusePA_k<<<786 + 1024, 256, 0, stream>>>(Wh, cfinb, head_b, out + (size_t)t * BB * VV,
                                                 memory, rpwp, dot_r, dot_w, norm2);
      else
        fusePA_k<<<786, 256, 0, stream>>>(Wh, cfinb, head_b, out + (size_t)t * BB * VV,
                                          memory, rpwp, dot_r, dot_w, norm2);
      addr_k<<<2 * BB, 256, 0, stream>>>(dot_r, dot_w, norm2, rpwp, read_w, write_w, ea, r_vec);
      if (t == 0)
        passB_k<1><<<dim3(NN / 128, BB), 256, 0, stream>>>(memory, write_w, read_w, ea, r_vec);
      else
        passB_k<0><<<dim3(NN / 128, BB), 256, 0, stream>>>(memory, write_w, read_w, ea, r_vec);
    } else {
      fusePA_k<<<786, 256, 0, stream>>>(Wh, cfinb, head_b, out + (size_t)t * BB * VV,
                                        memory, rpwp, dot_r, dot_w, norm2);
    }
  }
}

// Round 12
// 1401.604 us; speedup vs baseline: 1.1334x; 1.1334x over previous
//
#include <hip/hip_runtime.h>
#include <math.h>

#define TT 8
#define BB 32
#define VV 50257
#define DD 256
#define NN 4096
#define EPS_ 1e-12f

typedef __attribute__((ext_vector_type(8))) short short8;
typedef __attribute__((ext_vector_type(4))) float f32x4;

__device__ __forceinline__ float sigf(float x) { return 1.f / (1.f + expf(-x)); }
__device__ __forceinline__ float softplusf_(float x) { return fmaxf(x, 0.f) + log1pf(expf(-fabsf(x))); }
__device__ __forceinline__ unsigned f2bf(float f) {
  union { float f; unsigned u; } c; c.f = f;
  return (c.u + 0x7FFFu + ((c.u >> 16) & 1u)) >> 16;
}
__device__ __forceinline__ float bf2f(unsigned u16) {
  union { unsigned u; float f; } c; c.u = u16 << 16; return c.f;
}

// ---- block reductions (256-thread blocks only) ----
__device__ __forceinline__ float blk_sum(float v, float* s) {
#pragma unroll
  for (int o = 32; o > 0; o >>= 1) v += __shfl_down(v, o);
  __syncthreads();
  if ((threadIdx.x & 63) == 0) s[threadIdx.x >> 6] = v;
  __syncthreads();
  return s[0] + s[1] + s[2] + s[3];
}
__device__ __forceinline__ float blk_max(float v, float* s) {
#pragma unroll
  for (int o = 32; o > 0; o >>= 1) v = fmaxf(v, __shfl_down(v, o));
  __syncthreads();
  if ((threadIdx.x & 63) == 0) s[threadIdx.x >> 6] = v;
  __syncthreads();
  return fmaxf(fmaxf(s[0], s[1]), fmaxf(s[2], s[3]));
}

// ---- one-time init ----
__global__ void init_k(float* rw, float* ww, float* hpe) {
  int i = blockIdx.x * 256 + threadIdx.x;
  if (i < BB) { rw[(size_t)i * NN] = 1.f; ww[(size_t)i * NN] = 1.f; }
  if (i < BB * DD) hpe[i] = (i & 1) ? 1.f : 0.f;
}

__global__ void cvtw_k(const float* __restrict__ W, unsigned short* __restrict__ Wh, int n4) {
  int i = blockIdx.x * 256 + threadIdx.x;
  if (i >= n4) return;
  float4 v = *(const float4*)(W + (size_t)i * 4);
  uint2 p;
  p.x = f2bf(v.x) | (f2bf(v.y) << 16);
  p.y = f2bf(v.z) | (f2bf(v.w) << 16);
  *(uint2*)(Wh + (size_t)i * 4) = p;
}

__global__ void catlstm_k(const float* __restrict__ Wih, const float* __restrict__ Whh,
                          const float* __restrict__ bih, const float* __restrict__ bhh,
                          unsigned short* __restrict__ Wc, float* __restrict__ cb) {
  int i = blockIdx.x * 256 + threadIdx.x;
  if (i >= 2 * 1024 * 512) return;
  int k = i & 511, np = (i >> 9) & 1023, l = i >> 19;
  int d = np >> 2, gate = np & 3;
  int src = gate * 256 + d;
  float v = (k < 256) ? Wih[((size_t)l * 1024 + src) * 256 + k]
                      : Whh[((size_t)l * 1024 + src) * 256 + (k - 256)];
  Wc[i] = (unsigned short)f2bf(v);
  if (k == 0) cb[l * 1024 + np] = bih[l * 1024 + src] + bhh[l * 1024 + src];
}

__global__ void catrw_k(const float* __restrict__ rW, const float* __restrict__ rb,
                        const float* __restrict__ wW, const float* __restrict__ wb,
                        unsigned short* __restrict__ Wrw, float* __restrict__ brw) {
  int i = blockIdx.x * 256 + threadIdx.x;
  if (i >= 1036 * 256) return;
  int k = i & 255, n = i >> 8;
  float v = (n < 262) ? rW[(size_t)n * 256 + k] : wW[(size_t)(n - 262) * 256 + k];
  Wrw[i] = (unsigned short)f2bf(v);
  if (k == 0) brw[n] = (n < 262) ? rb[n] : wb[n - 262];
}

__global__ void brc_k(const float* __restrict__ fb, const float* __restrict__ rb, float* __restrict__ brc) {
  int i = blockIdx.x * 256 + threadIdx.x;
  if (i < 512) brc[i] = fb[i];
  else if (i < 768) brc[i] = rb[i - 512];
}

// ---- LN1(layer0) of ctx row 0 -> q1b ----
__global__ __launch_bounds__(256) void ln0_k(const float* __restrict__ hpe,
                                             const float* __restrict__ g1, const float* __restrict__ b1,
                                             unsigned short* __restrict__ q1b) {
  __shared__ float s8[8];
  int b = blockIdx.x, d = threadIdx.x;
  float v = hpe[(size_t)b * 256 + d];
  float mu = blk_sum(v, s8) * (1.f / 256.f);
  float dd = v - mu;
  float var = blk_sum(dd * dd, s8) * (1.f / 256.f);
  float rs = rsqrtf(var + 1e-5f);
  q1b[(size_t)b * 256 + d] = (unsigned short)f2bf(dd * rs * g1[d] + b1[d]);
}

// ---- gA f32 device body: 32m x 64n MFMA, K=256 ----
__device__ __forceinline__ void gA32f_dev(const unsigned short* __restrict__ A,
                                          const unsigned short* __restrict__ W,
                                          const float* __restrict__ bias,
                                          float* __restrict__ Cf, int ldc, int Nlim, int nblk) {
  const int tid = threadIdx.x, w = tid >> 6, l = tid & 63, r = l & 15, q = l >> 4;
  const int n = nblk * 64 + w * 16 + r;
  const unsigned short* Wp = W + (size_t)n * 256;
  f32x4 acc0 = {0.f, 0.f, 0.f, 0.f}, acc1 = {0.f, 0.f, 0.f, 0.f};
#pragma unroll
  for (int kt = 0; kt < 8; ++kt) {
    short8 a0 = *(const short8*)(A + r * 256 + kt * 32 + q * 8);
    short8 a1 = *(const short8*)(A + (16 + r) * 256 + kt * 32 + q * 8);
    short8 bf = *(const short8*)(Wp + kt * 32 + q * 8);
    acc0 = __builtin_amdgcn_mfma_f32_16x16x32_bf16(a0, bf, acc0, 0, 0, 0);
    acc1 = __builtin_amdgcn_mfma_f32_16x16x32_bf16(a1, bf, acc1, 0, 0, 0);
  }
  if (n >= Nlim) return;
  float bb = bias[n];
#pragma unroll
  for (int e = 0; e < 4; ++e) {
    int m1 = q * 4 + e, m2 = m1 + 16;
    Cf[(size_t)m1 * ldc + n] = acc0[e] + bb;
    Cf[(size_t)m2 * ldc + n] = acc1[e] + bb;
  }
}

// ---- gA kernel: 2D grid (n-tiles, m-tiles), f32 out ----
__global__ __launch_bounds__(256) void gA_k(const unsigned short* __restrict__ A,
                                            const unsigned short* __restrict__ W,
                                            const float* __restrict__ bias,
                                            float* __restrict__ Cf, int ldc, int Nlim) {
  gA32f_dev(A + (size_t)blockIdx.y * 32 * 256, W, bias,
            Cf + (size_t)blockIdx.y * 32 * ldc, ldc, Nlim, blockIdx.x);
}

// ---- gAr kernel: relu -> bf16 out (ffn1) ----
__global__ __launch_bounds__(256) void gAr_k(const unsigned short* __restrict__ A,
                                             const unsigned short* __restrict__ W,
                                             const float* __restrict__ bias,
                                             unsigned short* __restrict__ Cb, int ldc) {
  const int tid = threadIdx.x, w = tid >> 6, l = tid & 63, r = l & 15, q = l >> 4;
  const int n = blockIdx.x * 64 + w * 16 + r;
  const unsigned short* Ap = A + (size_t)blockIdx.y * 32 * 256;
  const unsigned short* Wp = W + (size_t)n * 256;
  f32x4 acc0 = {0.f, 0.f, 0.f, 0.f}, acc1 = {0.f, 0.f, 0.f, 0.f};
#pragma unroll
  for (int kt = 0; kt < 8; ++kt) {
    short8 a0 = *(const short8*)(Ap + r * 256 + kt * 32 + q * 8);
    short8 a1 = *(const short8*)(Ap + (16 + r) * 256 + kt * 32 + q * 8);
    short8 bf = *(const short8*)(Wp + kt * 32 + q * 8);
    acc0 = __builtin_amdgcn_mfma_f32_16x16x32_bf16(a0, bf, acc0, 0, 0, 0);
    acc1 = __builtin_amdgcn_mfma_f32_16x16x32_bf16(a1, bf, acc1, 0, 0, 0);
  }
  float bb = bias[n];
#pragma unroll
  for (int e = 0; e < 4; ++e) {
    int m1 = q * 4 + e, m2 = m1 + 16;
    Cb[(size_t)(blockIdx.y * 32 + m1) * ldc + n] = (unsigned short)f2bf(fmaxf(acc0[e] + bb, 0.f));
    Cb[(size_t)(blockIdx.y * 32 + m2) * ldc + n] = (unsigned short)f2bf(fmaxf(acc1[e] + bb, 0.f));
  }
}

// ---- gC kernel: 32m x 64n, templated K, out f32 = acc + bias + resid ----
template <int K>
__global__ __launch_bounds__(256) void gC_k(const unsigned short* __restrict__ A,
                                            const unsigned short* __restrict__ W,
                                            const float* __restrict__ bias,
                                            const float* __restrict__ resid,
                                            float* __restrict__ Hout) {
  const int tid = threadIdx.x, w = tid >> 6, l = tid & 63, r = l & 15, q = l >> 4;
  const int n = blockIdx.x * 64 + w * 16 + r;
  const int m0 = blockIdx.y * 32;
  const unsigned short* Ap = A + (size_t)m0 * K;
  const unsigned short* Wp = W + (size_t)n * K;
  f32x4 acc0 = {0.f, 0.f, 0.f, 0.f}, acc1 = {0.f, 0.f, 0.f, 0.f};
#pragma unroll 4
  for (int kt = 0; kt < K / 32; ++kt) {
    short8 a0 = *(const short8*)(Ap + (size_t)r * K + kt * 32 + q * 8);
    short8 a1 = *(const short8*)(Ap + (size_t)(16 + r) * K + kt * 32 + q * 8);
    short8 bf = *(const short8*)(Wp + kt * 32 + q * 8);
    acc0 = __builtin_amdgcn_mfma_f32_16x16x32_bf16(a0, bf, acc0, 0, 0, 0);
    acc1 = __builtin_amdgcn_mfma_f32_16x16x32_bf16(a1, bf, acc1, 0, 0, 0);
  }
  float bb = bias[n];
#pragma unroll
  for (int e = 0; e < 4; ++e) {
    int m1 = m0 + q * 4 + e, m2 = m1 + 16;
    Hout[(size_t)m1 * 256 + n] = acc0[e] + bb + resid[(size_t)m1 * 256 + n];
    Hout[(size_t)m2 * 256 + n] = acc1[e] + bb + resid[(size_t)m2 * 256 + n];
  }
}

// ---- addLN: row-LN over 32 rows/block of f32 H -> bf16 Xb (+optional f32 c_out) ----
__global__ __launch_bounds__(256) void addLN_k(const float* __restrict__ H,
                                               const float* __restrict__ g,
                                               const float* __restrict__ be,
                                               unsigned short* __restrict__ Xb, int xstride,
                                               float* __restrict__ c_out) {
  const int tid = threadIdx.x, w = tid >> 6, l = tid & 63;
  const int m0 = blockIdx.x * 32;
  const float4 g4 = *(const float4*)(g + l * 4);
  const float4 b4 = *(const float4*)(be + l * 4);
#pragma unroll
  for (int i = 0; i < 8; ++i) {
    int row = m0 + w * 8 + i;
    float4 v = *(const float4*)(H + (size_t)row * 256 + l * 4);
    float s1 = v.x + v.y + v.z + v.w;
    float s2 = v.x * v.x + v.y * v.y + v.z * v.z + v.w * v.w;
#pragma unroll
    for (int o = 32; o > 0; o >>= 1) { s1 += __shfl_xor(s1, o); s2 += __shfl_xor(s2, o); }
    float mu = s1 * (1.f / 256.f);
    float var = fmaxf(s2 * (1.f / 256.f) - mu * mu, 0.f);
    float rs = rsqrtf(var + 1e-5f);
    float y0 = (v.x - mu) * rs * g4.x + b4.x;
    float y1 = (v.y - mu) * rs * g4.y + b4.y;
    float y2 = (v.z - mu) * rs * g4.z + b4.z;
    float y3 = (v.w - mu) * rs * g4.w + b4.w;
    uint2 pk;
    pk.x = f2bf(y0) | (f2bf(y1) << 16);
    pk.y = f2bf(y2) | (f2bf(y3) << 16);
    *(uint2*)(Xb + (size_t)row * xstride + l * 4) = pk;
    if (c_out) {
      float4 cv = make_float4(y0, y1, y2, y3);
      *(float4*)(c_out + (size_t)row * 256 + l * 4) = cv;
    }
  }
}

// ---- aux: rw-param GEMM (blocks 0..16) + film GEMM (17..28) ----
__global__ __launch_bounds__(256) void auxg_k(const unsigned short* __restrict__ cfinb,
                                              const unsigned short* __restrict__ Wrw,
                                              const float* __restrict__ brw, float* __restrict__ rpwp,
                                              const unsigned short* __restrict__ record_b,
                                              const unsigned short* __restrict__ FRw,
                                              const float* __restrict__ brc, float* __restrict__ fp) {
  if (blockIdx.x < 17) gA32f_dev(cfinb, Wrw, brw, rpwp, 1036, 1036, blockIdx.x);
  else gA32f_dev(record_b, FRw, brc, fp, 768, 768, blockIdx.x - 17);
}

// ---- full multi-head attention over S<=9 rows (layer 1), bf16 out ----
__global__ __launch_bounds__(128) void attn_k(const float* __restrict__ qkv,
                                              unsigned short* __restrict__ ao, int S) {
  int bh = blockIdx.x;
  int b = bh >> 2, h = bh & 3;
  __shared__ float q[9][64], k[9][64], v[9][64], lg[9][12];
  int tid = threadIdx.x;
  for (int i = tid; i < S * 64; i += 128) {
    int s = i >> 6, d = i & 63;
    const float* base = qkv + (size_t)(s * BB + b) * 768 + h * 64 + d;
    q[s][d] = base[0]; k[s][d] = base[256]; v[s][d] = base[512];
  }
  __syncthreads();
  for (int p = tid; p < S * S; p += 128) {
    int s = p / S, t2 = p % S;
    float acc = 0.f;
    for (int d = 0; d < 64; ++d) acc += q[s][d] * k[t2][d];
    lg[s][t2] = acc * 0.125f;
  }
  __syncthreads();
  if (tid < S) {
    float mx = -1e30f;
    for (int t2 = 0; t2 < S; ++t2) mx = fmaxf(mx, lg[tid][t2]);
    float sum = 0.f;
    for (int t2 = 0; t2 < S; ++t2) { float e = expf(lg[tid][t2] - mx); lg[tid][t2] = e; sum += e; }
    float inv = 1.f / sum;
    for (int t2 = 0; t2 < S; ++t2) lg[tid][t2] *= inv;
  }
  __syncthreads();
  for (int i = tid; i < S * 64; i += 128) {
    int s = i >> 6, d = i & 63;
    float o = 0.f;
    for (int t2 = 0; t2 < S; ++t2) o += lg[s][t2] * v[t2][d];
    ao[(size_t)(s * BB + b) * 256 + h * 64 + d] = (unsigned short)f2bf(o);
  }
}

// ---- last-row-only attention (layer 2), bf16 out ----
__global__ __launch_bounds__(64) void attnl_k(const float* __restrict__ qkv,
                                              unsigned short* __restrict__ ao, int S) {
  int bh = blockIdx.x;
  int b = bh >> 2, h = bh & 3;
  int d = threadIdx.x;
  __shared__ float sc[9];
  float qd = qkv[(size_t)((S - 1) * BB + b) * 768 + h * 64 + d];
  for (int j = 0; j < S; ++j) {
    float p = qd * qkv[(size_t)(j * BB + b) * 768 + h * 64 + 256 + d];
#pragma unroll
    for (int o = 32; o > 0; o >>= 1) p += __shfl_down(p, o);
    if (d == 0) sc[j] = p * 0.125f;
  }
  __syncthreads();
  float mx = -1e30f;
  for (int j = 0; j < S; ++j) mx = fmaxf(mx, sc[j]);
  float pj[9], sum = 0.f;
  for (int j = 0; j < S; ++j) { pj[j] = expf(sc[j] - mx); sum += pj[j]; }
  float inv = 1.f / sum;
  float o = 0.f;
  for (int j = 0; j < S; ++j) o += pj[j] * inv * qkv[(size_t)(j * BB + b) * 768 + h * 64 + 512 + d];
  ao[(size_t)b * 256 + h * 64 + d] = (unsigned short)f2bf(o);
}

// ======= LSTM MFMA GEMM (K=512, gate-interleaved N=1024) + pointwise epilogue =======
template <int LAST>
__global__ __launch_bounds__(256) void gL_k(const unsigned short* __restrict__ A,
                                            const unsigned short* __restrict__ W,
                                            const float* __restrict__ cbias,
                                            float* __restrict__ cx,
                                            unsigned short* __restrict__ li_own,
                                            unsigned short* __restrict__ li_next,
                                            const float* __restrict__ c_outp,
                                            unsigned short* __restrict__ cfinb,
                                            unsigned short* __restrict__ record_b) {
  __shared__ float g[32][68];
  const int tid = threadIdx.x, w = tid >> 6, l = tid & 63, r = l & 15, q = l >> 4;
  const int n = blockIdx.x * 64 + w * 16 + r;
  const unsigned short* Wp = W + (size_t)n * 512;
  f32x4 acc0 = {0.f, 0.f, 0.f, 0.f}, acc1 = {0.f, 0.f, 0.f, 0.f};
#pragma unroll 4
  for (int kt = 0; kt < 16; ++kt) {
    short8 a0 = *(const short8*)(A + (size_t)r * 512 + kt * 32 + q * 8);
    short8 a1 = *(const short8*)(A + (size_t)(16 + r) * 512 + kt * 32 + q * 8);
    short8 bf = *(const short8*)(Wp + kt * 32 + q * 8);
    acc0 = __builtin_amdgcn_mfma_f32_16x16x32_bf16(a0, bf, acc0, 0, 0, 0);
    acc1 = __builtin_amdgcn_mfma_f32_16x16x32_bf16(a1, bf, acc1, 0, 0, 0);
  }
  float bb = cbias[n];
  int nb = w * 16 + r;
#pragma unroll
  for (int e = 0; e < 4; ++e) {
    g[q * 4 + e][nb] = acc0[e] + bb;
    g[16 + q * 4 + e][nb] = acc1[e] + bb;
  }
  __syncthreads();
#pragma unroll
  for (int h2 = 0; h2 < 2; ++h2) {
    int u = tid + 256 * h2;
    int b = u >> 4, dd = u & 15;
    int dg = blockIdx.x * 16 + dd;
    float gi = g[b][dd * 4 + 0], gf = g[b][dd * 4 + 1];
    float gg = g[b][dd * 4 + 2], go = g[b][dd * 4 + 3];
    float c = sigf(gf) * cx[b * 256 + dg] + sigf(gi) * tanhf(gg);
    float hN = sigf(go) * tanhf(c);
    cx[b * 256 + dg] = c;
    li_own[(size_t)b * 512 + 256 + dg] = (unsigned short)f2bf(hN);
    if constexpr (LAST) {
      record_b[b * 256 + dg] = (unsigned short)f2bf(hN);
      cfinb[b * 256 + dg] = (unsigned short)f2bf(c_outp[b * 256 + dg] + hN);
    } else {
      li_next[(size_t)b * 512 + dg] = (unsigned short)f2bf(hN);
    }
  }
}

// ---- xin pointwise: FiLM nonlin + emb + gated read + PE -> hpe row; LN1 -> q1b ----
__global__ __launch_bounds__(256) void xinpw_k(const int* __restrict__ tokens,
                                               const float* __restrict__ embW,
                                               const float* __restrict__ fp,
                                               const float* __restrict__ rvec,
                                               const float* __restrict__ g1, const float* __restrict__ b1,
                                               float* __restrict__ hpe,
                                               unsigned short* __restrict__ q1b, int t) {
  __shared__ float s8[8];
  int b = blockIdx.x, d = threadIdx.x;
  float gam = 1.f + tanhf(fp[(size_t)b * 768 + d]);
  float bet = fp[(size_t)b * 768 + 256 + d];
  float rg = sigf(fp[(size_t)b * 768 + 512 + d]);
  int tok = tokens[t * BB + b];
  float emb = embW[(size_t)tok * 256 + d];
  float ang = (float)(t + 1) * expf(-logf(10000.f) * (float)(d & ~1) / 256.f);
  float pe = (d & 1) ? cosf(ang) : sinf(ang);
  float x = gam * emb + bet + rg * rvec[b * 256 + d] + pe;
  hpe[((size_t)(t + 1) * BB + b) * 256 + d] = x;
  float mu = blk_sum(x, s8) * (1.f / 256.f);
  float dd = x - mu;
  float var = blk_sum(dd * dd, s8) * (1.f / 256.f);
  float rs = rsqrtf(var + 1e-5f);
  q1b[((size_t)(t + 1) * BB + b) * 256 + d] = (unsigned short)f2bf(dd * rs * g1[d] + b1[d]);
}

// ======= fused head (blocks 0..785) + MFMA passA (786..786+1024) =======
__global__ __launch_bounds__(256) void fusePA_k(const unsigned short* __restrict__ Wh,
                                                const unsigned short* __restrict__ Ah,
                                                const float* __restrict__ hb,
                                                float* __restrict__ out,
                                                const unsigned short* __restrict__ mem,
                                                const float* __restrict__ rpwp,
                                                float* __restrict__ dr,
                                                float* __restrict__ dw,
                                                float* __restrict__ nrm) {
  __shared__ unsigned short kS[4][256];
  const int bid = blockIdx.x;
  const int tid = threadIdx.x;
  if (bid < 786) {
    const int w = tid >> 6, l = tid & 63;
    const int r = l & 15, q = l >> 4;
    const int n = bid * 64 + w * 16 + r;
    const int nc = n < VV ? n : VV - 1;
    const short* Ap = (const short*)Ah;
    const short* Wp = (const short*)Wh + (size_t)nc * 256;
    short8 a0[8], a1[8], bf[8];
#pragma unroll
    for (int kt = 0; kt < 8; ++kt) {
      a0[kt] = *(const short8*)(Ap + r * 256 + kt * 32 + q * 8);
      a1[kt] = *(const short8*)(Ap + (16 + r) * 256 + kt * 32 + q * 8);
      bf[kt] = *(const short8*)(Wp + kt * 32 + q * 8);
    }
    f32x4 acc0 = {0.f, 0.f, 0.f, 0.f}, acc1 = {0.f, 0.f, 0.f, 0.f};
#pragma unroll
    for (int kt = 0; kt < 8; ++kt) {
      acc0 = __builtin_amdgcn_mfma_f32_16x16x32_bf16(a0[kt], bf[kt], acc0, 0, 0, 0);
      acc1 = __builtin_amdgcn_mfma_f32_16x16x32_bf16(a1[kt], bf[kt], acc1, 0, 0, 0);
    }
    if (n < VV) {
      float bb = hb[n];
#pragma unroll
      for (int e = 0; e < 4; ++e) {
        int m = q * 4 + e;
        out[(size_t)m * VV + n] = acc0[e] + bb;
        out[(size_t)(16 + m) * VV + n] = acc1[e] + bb;
      }
    }
    return;
  }
  const int idx = bid - 786;
  const int bx = idx & 31, by = idx >> 5;
  {
    float kr = rpwp[(size_t)by * 1036 + tid];
    float kw = rpwp[(size_t)by * 1036 + 262 + tid];
    unsigned krh = f2bf(kr), kwh = f2bf(kw);
    kS[0][tid] = (unsigned short)krh;
    kS[1][tid] = (unsigned short)kwh;
    kS[2][tid] = (unsigned short)f2bf(kr - bf2f(krh));
    kS[3][tid] = (unsigned short)f2bf(kw - bf2f(kwh));
  }
  __syncthreads();
  const int w = tid >> 6, l = tid & 63, col = l & 15, ko = (l >> 4) * 8;
  short8 bfrag[8];
#pragma unroll
  for (int kt = 0; kt < 8; ++kt) {
    if (col < 4) bfrag[kt] = *(const short8*)(&kS[col][kt * 32 + ko]);
    else bfrag[kt] = short8{0, 0, 0, 0, 0, 0, 0, 0};
  }
  const int base = bx * 128 + w * 32;
  const unsigned short* Ap0 = mem + ((size_t)by * NN + base + col) * 256 + ko;
  const unsigned short* Ap1 = mem + ((size_t)by * NN + base + 16 + col) * 256 + ko;
  f32x4 acc0 = {0.f, 0.f, 0.f, 0.f}, acc1 = {0.f, 0.f, 0.f, 0.f};
  float pn0 = 0.f, pn1 = 0.f;
#pragma unroll
  for (int kt = 0; kt < 8; ++kt) {
    short8 a0 = *(const short8*)(Ap0 + kt * 32);
    short8 a1 = *(const short8*)(Ap1 + kt * 32);
    acc0 = __builtin_amdgcn_mfma_f32_16x16x32_bf16(a0, bfrag[kt], acc0, 0, 0, 0);
    acc1 = __builtin_amdgcn_mfma_f32_16x16x32_bf16(a1, bfrag[kt], acc1, 0, 0, 0);
#pragma unroll
    for (int j = 0; j < 8; ++j) {
      float v0 = bf2f((unsigned short)a0[j]);
      float v1 = bf2f((unsigned short)a1[j]);
      pn0 += v0 * v0;
      pn1 += v1 * v1;
    }
  }
  pn0 += __shfl_xor(pn0, 16); pn0 += __shfl_xor(pn0, 32);
  pn1 += __shfl_xor(pn1, 16); pn1 += __shfl_xor(pn1, 32);
  if (l < 16) {
    nrm[(size_t)by * NN + base + l] = pn0;
    nrm[(size_t)by * NN + base + 16 + l] = pn1;
  }
#pragma unroll
  for (int e = 0; e < 4; ++e) {
    float s0 = acc0[e] + __shfl_xor(acc0[e], 2);
    float s1 = acc1[e] + __shfl_xor(acc1[e], 2);
    int row = (l >> 4) * 4 + e;
    if (col == 0) {
      dr[(size_t)by * NN + base + row] = s0;
      dr[(size_t)by * NN + base + 16 + row] = s1;
    } else if (col == 1) {
      dw[(size_t)by * NN + base + row] = s0;
      dw[(size_t)by * NN + base + 16 + row] = s1;
    }
  }
}

// ---- addressing ----
__global__ __launch_bounds__(256) void addr_k(const float* __restrict__ dr,
                                              const float* __restrict__ dw,
                                              const float* __restrict__ nrm,
                                              const float* __restrict__ rpwp,
                                              float* rw, float* ww,
                                              float* __restrict__ ea,
                                              float* __restrict__ rvec) {
  __shared__ float wg[4096];
  __shared__ float s8[8];
  int head = blockIdx.x & 1, b = blockIdx.x >> 1;
  int tid = threadIdx.x;
  const float* p = rpwp + (size_t)b * 1036 + (head ? 262 : 0);
  const float* dot = (head ? dw : dr) + (size_t)b * NN;
  const float* n2 = nrm + (size_t)b * NN;
  float* wout = (head ? ww : rw) + (size_t)b * NN;

  float kv = p[tid];
  float kn = sqrtf(blk_sum(kv * kv, s8)) + EPS_;
  float beta = p[256], gate = p[257], sh0 = p[258], sh1 = p[259], sh2 = p[260], gamma = p[261];
  float spb = softplusf_(beta);
  float g = sigf(gate);
  float mx3 = fmaxf(sh0, fmaxf(sh1, sh2));
  float e0 = expf(sh0 - mx3), e1 = expf(sh1 - mx3), e2 = expf(sh2 - mx3);
  float esum = e0 + e1 + e2;
  float s0 = e0 / esum, s1 = e1 / esum, s2 = e2 / esum;
  float gp = 1.f + softplusf_(gamma);

  float l[16];
  float lmax = -1e30f;
#pragma unroll
  for (int i = 0; i < 16; ++i) {
    int n = tid + i * 256;
    float cs = dot[n] / ((sqrtf(n2[n]) + EPS_) * kn);
    l[i] = spb * cs;
    lmax = fmaxf(lmax, l[i]);
  }
  float Mx = blk_max(lmax, s8);
  float es = 0.f;
#pragma unroll
  for (int i = 0; i < 16; ++i) { l[i] = expf(l[i] - Mx); es += l[i]; }
  float SS = blk_sum(es, s8);
  float inv = 1.f / SS;
#pragma unroll
  for (int i = 0; i < 16; ++i) {
    int n = tid + i * 256;
    wg[n] = g * l[i] * inv + (1.f - g) * wout[n];
  }
  __syncthreads();
  float wt[16];
  float wsum = 0.f;
#pragma unroll
  for (int i = 0; i < 16; ++i) {
    int n = tid + i * 256;
    float sh = s0 * wg[(n + 1) & 4095] + s1 * wg[n] + s2 * wg[(n + 4095) & 4095];
    wt[i] = powf(sh + EPS_, gp);
    wsum += wt[i];
  }
  float WS = blk_sum(wsum, s8) + EPS_;
  float winv = 1.f / WS;
#pragma unroll
  for (int i = 0; i < 16; ++i) wout[tid + i * 256] = wt[i] * winv;

  if (head) {
    ea[(size_t)b * 512 + tid] = sigf(p[262 + tid]);
    ea[(size_t)b * 512 + 256 + tid] = tanhf(p[518 + tid]);
  } else {
    rvec[(size_t)b * 256 + tid] = 0.f;
  }
}

// ---- pass B over bf16 memory: erase/add + fused r = rw . mem_new ----
template <int FIRST>
__global__ __launch_bounds__(256) void passB_k(unsigned short* mem, const float* __restrict__ ww,
                                               const float* __restrict__ rw,
                                               const float* __restrict__ ea,
                                               float* __restrict__ rvec) {
  __shared__ float eS[256], aS[256];
  __shared__ float rred[4][256];
  int b = blockIdx.y, tid = threadIdx.x;
  eS[tid] = ea[(size_t)b * 512 + tid];
  aS[tid] = ea[(size_t)b * 512 + 256 + tid];
  __syncthreads();
  int w = tid >> 6, lane = tid & 63;
  float4 e4 = *(float4*)&eS[lane * 4];
  float4 a4 = *(float4*)&aS[lane * 4];
  float4 racc = make_float4(0.f, 0.f, 0.f, 0.f);
  int n0 = blockIdx.x * 128 + w * 32;
  for (int rr = 0; rr < 32; ++rr) {
    int n = n0 + rr;
    float wt = ww[(size_t)b * NN + n];
    float rwv = rw[(size_t)b * NN + n];
    unsigned short* row = mem + ((size_t)b * NN + n) * 256;
    float m0, m1, m2, m3;
    if (FIRST) {
      m0 = wt * a4.x; m1 = wt * a4.y; m2 = wt * a4.z; m3 = wt * a4.w;
    } else {
      uint2 p = *(const uint2*)(row + lane * 4);
      m0 = bf2f(p.x & 0xffffu) * (1.f - wt * e4.x) + wt * a4.x;
      m1 = bf2f(p.x >> 16) * (1.f - wt * e4.y) + wt * a4.y;
      m2 = bf2f(p.y & 0xffffu) * (1.f - wt * e4.z) + wt * a4.z;
      m3 = bf2f(p.y >> 16) * (1.f - wt * e4.w) + wt * a4.w;
    }
    uint2 pk;
    pk.x = f2bf(m0) | (f2bf(m1) << 16);
    pk.y = f2bf(m2) | (f2bf(m3) << 16);
    *(uint2*)(row + lane * 4) = pk;
    racc.x += rwv * m0; racc.y += rwv * m1; racc.z += rwv * m2; racc.w += rwv * m3;
  }
  rred[w][lane * 4 + 0] = racc.x;
  rred[w][lane * 4 + 1] = racc.y;
  rred[w][lane * 4 + 2] = racc.z;
  rred[w][lane * 4 + 3] = racc.w;
  __syncthreads();
  float s = rred[0][tid] + rred[1][tid] + rred[2][tid] + rred[3][tid];
  atomicAdd(rvec + (size_t)b * 256 + tid, s);
}

extern "C" void kernel_launch(void* const* d_in, const int* in_sizes, int n_in,
                              void* d_out, int out_size, void* d_ws, size_t ws_size,
                              hipStream_t stream) {
  const int* tokens = (const int*)d_in[0];
  const float* emb_W = (const float*)d_in[1];
  const float* read_gate_W = (const float*)d_in[2];
  const float* read_gate_b = (const float*)d_in[3];
  const float* film_W = (const float*)d_in[4];
  const float* film_b = (const float*)d_in[5];
  const float* t_Wqkv = (const float*)d_in[6];
  const float* t_bqkv = (const float*)d_in[7];
  const float* t_Wo = (const float*)d_in[8];
  const float* t_bo = (const float*)d_in[9];
  const float* t_ln1_g = (const float*)d_in[10];
  const float* t_ln1_b = (const float*)d_in[11];
  const float* t_ln2_g = (const float*)d_in[12];
  const float* t_ln2_b = (const float*)d_in[13];
  const float* t_W1 = (const float*)d_in[14];
  const float* t_b1 = (const float*)d_in[15];
  const float* t_W2 = (const float*)d_in[16];
  const float* t_b2 = (const float*)d_in[17];
  const float* out_ln_g = (const float*)d_in[18];
  const float* out_ln_b = (const float*)d_in[19];
  const float* lstm_Wih = (const float*)d_in[20];
  const float* lstm_Whh = (const float*)d_in[21];
  const float* lstm_bih = (const float*)d_in[22];
  const float* lstm_bhh = (const float*)d_in[23];
  const float* head_W = (const float*)d_in[24];
  const float* head_b = (const float*)d_in[25];
  const float* read_W = (const float*)d_in[26];
  const float* read_b = (const float*)d_in[27];
  const float* write_W = (const float*)d_in[28];
  const float* write_b = (const float*)d_in[29];
  float* out = (float*)d_out;

  float* ws = (float*)d_ws;
  size_t off = 0;
  // ---- zero-initialized region ----
  float* read_w = ws + off; off += (size_t)BB * NN;
  float* write_w = ws + off; off += (size_t)BB * NN;
  float* cx = ws + off; off += 2 * BB * DD;
  float* r_vec = ws + off; off += BB * DD;
  float* dot_r = ws + off; off += (size_t)BB * NN;
  float* dot_w = ws + off; off += (size_t)BB * NN;
  float* norm2 = ws + off; off += (size_t)BB * NN;
  unsigned short* record_b = (unsigned short*)(ws + off); off += BB * DD / 2;
  unsigned short* lstm_in_b = (unsigned short*)(ws + off); off += 2 * BB * 512 / 2;
  size_t zero_floats = off;
  // ---- not zeroed ----
  unsigned short* memory = (unsigned short*)(ws + off); off += (size_t)BB * NN * DD / 2;
  float* hpe = ws + off; off += 9 * BB * DD;
  float* h = ws + off; off += 9 * BB * DD;
  float* h2 = ws + off; off += BB * DD;
  float* qkvC = ws + off; off += 9 * BB * 768;
  float* qkv2 = ws + off; off += 9 * BB * 768;
  float* fp = ws + off; off += BB * 768;
  float* c_out = ws + off; off += BB * DD;
  float* rpwp = ws + off; off += BB * 1036;
  float* ea = ws + off; off += BB * 2 * DD;
  unsigned short* q1b = (unsigned short*)(ws + off); off += 9 * BB * DD / 2;
  unsigned short* q2b = (unsigned short*)(ws + off); off += 9 * BB * DD / 2;
  unsigned short* x2b = (unsigned short*)(ws + off); off += 9 * BB * DD / 2;
  unsigned short* x2b2 = (unsigned short*)(ws + off); off += BB * DD / 2;
  unsigned short* ao1_b = (unsigned short*)(ws + off); off += 9 * BB * DD / 2;
  unsigned short* ao2_b = (unsigned short*)(ws + off); off += BB * DD / 2;
  unsigned short* mid_b = (unsigned short*)(ws + off); off += 9 * BB * 1024 / 2;
  unsigned short* cfinb = (unsigned short*)(ws + off); off += BB * DD / 2;
  unsigned short* Wh = (unsigned short*)(ws + off); off += (size_t)VV * 256 / 2;
  unsigned short* Wq_b = (unsigned short*)(ws + off); off += 2 * 768 * 256 / 2;
  unsigned short* Wo_b = (unsigned short*)(ws + off); off += 2 * 256 * 256 / 2;
  unsigned short* W1_b = (unsigned short*)(ws + off); off += 2 * 1024 * 256 / 2;
  unsigned short* W2_b = (unsigned short*)(ws + off); off += 2 * 256 * 1024 / 2;
  unsigned short* Wc_b = (unsigned short*)(ws + off); off += 2 * 1024 * 512 / 2;
  unsigned short* Wrw_b = (unsigned short*)(ws + off); off += 1088 * 256 / 2;
  unsigned short* FR_b = (unsigned short*)(ws + off); off += 768 * 256 / 2;
  float* cb2 = ws + off; off += 2 * 1024;
  float* brw = ws + off; off += 1040;
  float* brc = ws + off; off += 768;
  if (ws_size < off * sizeof(float)) return;

  (void)hipMemsetAsync(ws, 0, zero_floats * sizeof(float), stream);
  (void)hipMemsetAsync(Wrw_b + (size_t)1036 * 256, 0, (size_t)52 * 256 * 2, stream);
  init_k<<<32, 256, 0, stream>>>(read_w, write_w, hpe);
  cvtw_k<<<(VV * 256 / 4 + 255) / 256, 256, 0, stream>>>(head_W, Wh, VV * 256 / 4);
  cvtw_k<<<(2 * 768 * 256 / 4 + 255) / 256, 256, 0, stream>>>(t_Wqkv, Wq_b, 2 * 768 * 256 / 4);
  cvtw_k<<<(2 * 256 * 256 / 4 + 255) / 256, 256, 0, stream>>>(t_Wo, Wo_b, 2 * 256 * 256 / 4);
  cvtw_k<<<(2 * 1024 * 256 / 4 + 255) / 256, 256, 0, stream>>>(t_W1, W1_b, 2 * 1024 * 256 / 4);
  cvtw_k<<<(2 * 256 * 1024 / 4 + 255) / 256, 256, 0, stream>>>(t_W2, W2_b, 2 * 256 * 1024 / 4);
  cvtw_k<<<(512 * 256 / 4 + 255) / 256, 256, 0, stream>>>(film_W, FR_b, 512 * 256 / 4);
  cvtw_k<<<(256 * 256 / 4 + 255) / 256, 256, 0, stream>>>(read_gate_W, FR_b + 512 * 256, 256 * 256 / 4);
  catlstm_k<<<4096, 256, 0, stream>>>(lstm_Wih, lstm_Whh, lstm_bih, lstm_bhh, Wc_b, cb2);
  catrw_k<<<1036, 256, 0, stream>>>(read_W, read_b, write_W, write_b, Wrw_b, brw);
  brc_k<<<3, 256, 0, stream>>>(film_b, read_gate_b, brc);
  ln0_k<<<BB, 256, 0, stream>>>(hpe, t_ln1_g, t_ln1_b, q1b);
  gA_k<<<dim3(12, 1), 256, 0, stream>>>(q1b, Wq_b, t_bqkv, qkvC, 768, 768);
  gA_k<<<dim3(12, 1), 256, 0, stream>>>(record_b, FR_b, brc, fp, 768, 768);  // film t=0

  for (int t = 0; t < TT; ++t) {
    const int S = t + 2;

    xinpw_k<<<BB, 256, 0, stream>>>(tokens, emb_W, fp, r_vec, t_ln1_g, t_ln1_b, hpe, q1b, t);
    gA_k<<<dim3(12, 1), 256, 0, stream>>>(q1b + (size_t)(t + 1) * BB * 256, Wq_b, t_bqkv,
                                          qkvC + (size_t)(t + 1) * BB * 768, 768, 768);
    attn_k<<<BB * 4, 128, 0, stream>>>(qkvC, ao1_b, S);
    gC_k<256><<<dim3(4, S), 256, 0, stream>>>(ao1_b, Wo_b, t_bo, hpe, h);
    addLN_k<<<S, 256, 0, stream>>>(h, t_ln2_g, t_ln2_b, x2b, 256, nullptr);
    gAr_k<<<dim3(16, S), 256, 0, stream>>>(x2b, W1_b, t_b1, mid_b, 1024);
    gC_k<1024><<<dim3(4, S), 256, 0, stream>>>(mid_b, W2_b, t_b2, h, h);
    addLN_k<<<S, 256, 0, stream>>>(h, t_ln1_g + 256, t_ln1_b + 256, q2b, 256, nullptr);
    // layer-2
    gA_k<<<dim3(12, S), 256, 0, stream>>>(q2b, Wq_b + 768 * 256, t_bqkv + 768, qkv2, 768, 768);
    attnl_k<<<BB * 4, 64, 0, stream>>>(qkv2, ao2_b, S);
    gC_k<256><<<dim3(4, 1), 256, 0, stream>>>(ao2_b, Wo_b + 256 * 256, t_bo + 256,
                                              h + (size_t)(S - 1) * BB * 256, h2);
    addLN_k<<<1, 256, 0, stream>>>(h2, t_ln2_g + 256, t_ln2_b + 256, x2b2, 256, nullptr);
    gAr_k<<<dim3(16, 1), 256, 0, stream>>>(x2b2, W1_b + 1024 * 256, t_b1 + 1024, mid_b, 1024);
    gC_k<1024><<<dim3(4, 1), 256, 0, stream>>>(mid_b, W2_b + 256 * 1024, t_b2 + 256, h2, h2);
    addLN_k<<<1, 256, 0, stream>>>(h2, out_ln_g, out_ln_b, lstm_in_b, 512, c_out);
    // LSTM
    gL_k<0><<<16, 256, 0, stream>>>(lstm_in_b, Wc_b, cb2, cx, lstm_in_b, lstm_in_b + BB * 512,
                                    nullptr, nullptr, nullptr);
    gL_k<1><<<16, 256, 0, stream>>>(lstm_in_b + BB * 512, Wc_b + (size_t)1024 * 512, cb2 + 1024,
                                    cx + BB * DD, lstm_in_b + BB * 512, nullptr, c_out, cfinb, record_b);
    // aux GEMMs then head || passA
    if (t < TT - 1) {
      auxg_k<<<29, 256, 0, stream>>>(cfinb, Wrw_b, brw, rpwp, record_b, FR_b, brc, fp);
      if (t > 0)
        fusePA_k<<<786 + 1024, 256, 0, stream>>>(Wh, cfinb, head_b, out + (size_t)t * BB * VV,
                                                 memory, rpwp, dot_r, dot_w, norm2);
      else
        fusePA_k<<<786, 256, 0, stream>>>(Wh, cfinb, head_b, out + (size_t)t * BB * VV,
                                          memory, rpwp, dot_r, dot_w, norm2);
      addr_k<<<2 * BB, 256, 0, stream>>>(dot_r, dot_w, norm2, rpwp, read_w, write_w, ea, r_vec);
      if (t == 0)
        passB_k<1><<<dim3(NN / 128, BB), 256, 0, stream>>>(memory, write_w, read_w, ea, r_vec);
      else
        passB_k<0><<<dim3(NN / 128, BB), 256, 0, stream>>>(memory, write_w, read_w, ea, r_vec);
    } else {
      fusePA_k<<<786, 256, 0, stream>>>(Wh, cfinb, head_b, out + (size_t)t * BB * VV,
                                        memory, rpwp, dot_r, dot_w, norm2);
    }
  }
}